// Round 4
// baseline (219.228 us; speedup 1.0000x reference)
//
#include <hip/hip_runtime.h>
#include <hip/hip_bf16.h>
#include <stdint.h>

#define B_  32
#define L_  512
#define D_  256
#define K_  65
#define KK  4225       // K_*K_
#define NP  4352       // padded N (34 * 128)
#define M_  16384      // B_*L_
#define MSTR 4352      // per-matrix element stride (65x65 compact rows + pad)
#define LSTR2 128      // chain LDS row stride (16 groups of 8 for XOR swizzle)
#define LMAT2 12288    // 96*128 elems

typedef __attribute__((ext_vector_type(8))) short bf16x8;
typedef __attribute__((ext_vector_type(4))) float f32x4;

typedef unsigned int u32g __attribute__((address_space(1)));
typedef unsigned int u32l __attribute__((address_space(3)));

__device__ __forceinline__ void async_ld16(const void* g, void* l) {
  __builtin_amdgcn_global_load_lds((const u32g*)g, (u32l*)l, 16, 0, 0);
}

// chain LDS [96][128]: XOR row into col-group (16 groups of 8) -> 2-way banks
__device__ __forceinline__ int swzc(int row, int col) {
  return row * LSTR2 + ((col & 7) | ((((col >> 3) ^ row) & 15) << 3));
}
// gemm LDS [128][64]: XOR row into col-group (8 groups of 8) -> 2-way banks
__device__ __forceinline__ int swzg(int row, int col) {
  return row * 64 + ((col & 7) | ((((col >> 3) ^ row) & 7) << 3));
}

// ---------------- prep: W' = Wt + Ws (bf16), bias' = bt + bs ----------------
__global__ __launch_bounds__(256) void pack_w_kernel(
    const float* __restrict__ Ws, const float* __restrict__ Wt,
    const float* __restrict__ bs, const float* __restrict__ bt,
    __hip_bfloat16* __restrict__ wbf, float* __restrict__ bias) {
  int p = blockIdx.x;   // 0..NP-1
  int d = threadIdx.x;  // 0..255
  float v = 0.f;
  if (p < KK) {
    int j = p % K_;
    v = Wt[(size_t)p * D_ + d] + Ws[(size_t)j * D_ + d];
    if (d == 0) bias[p] = bt[p] + bs[j];
  } else {
    if (d == 0) bias[p] = 0.f;
  }
  wbf[(size_t)p * D_ + d] = __float2bfloat16(v);
}

// ---------------- prep: x -> bf16 ----------------
__global__ __launch_bounds__(256) void pack_x_kernel(
    const float* __restrict__ x, __hip_bfloat16* __restrict__ xbf) {
  int idx = blockIdx.x * 256 + threadIdx.x;  // float4 index, total M_*D_/4
  float4 v = ((const float4*)x)[idx];
  __hip_bfloat16 o[4] = {__float2bfloat16(v.x), __float2bfloat16(v.y),
                         __float2bfloat16(v.z), __float2bfloat16(v.w)};
  *(uint2*)(xbf + (size_t)idx * 4) = *(const uint2*)o;
}

// ---------------- GEMM: F = exp((A*B^T + bias) * mask), fused tgt gather ----
__global__ __launch_bounds__(256) void gemm_exp_kernel(
    const __hip_bfloat16* __restrict__ A, const __hip_bfloat16* __restrict__ Bm,
    const float* __restrict__ bias, const float* __restrict__ mask,
    const int* __restrict__ target,
    __hip_bfloat16* __restrict__ F, float* __restrict__ tgtE) {
  __shared__ __align__(16) __hip_bfloat16 As[128 * 64];
  __shared__ __align__(16) __hip_bfloat16 Bs[128 * 64];
  int tid = threadIdx.x;
  int mBase = blockIdx.x * 128;
  int nBase = blockIdx.y * 128;
  int wid = tid >> 6, lane = tid & 63;
  int wm = (wid >> 1) * 64, wn = (wid & 1) * 64;
  int lrow = lane & 15, lk = (lane >> 4) * 8;

  f32x4 acc[4][4];
#pragma unroll
  for (int a = 0; a < 4; ++a)
#pragma unroll
    for (int c = 0; c < 4; ++c) acc[a][c] = (f32x4){0.f, 0.f, 0.f, 0.f};

  // pre-swizzled global source column-group (LDS dest stays linear)
  int gsrc = (((tid & 7) ^ ((tid >> 3) & 7))) * 8;
  const __hip_bfloat16* aSrc = A + (size_t)(mBase + (tid >> 3)) * D_ + gsrc;
  const __hip_bfloat16* bSrc = Bm + (size_t)(nBase + (tid >> 3)) * D_ + gsrc;
  char* aDst = (char*)As + tid * 16;
  char* bDst = (char*)Bs + tid * 16;

  for (int kt = 0; kt < D_; kt += 64) {
#pragma unroll
    for (int i = 0; i < 4; ++i) {
      async_ld16(aSrc + (size_t)i * 32 * D_ + kt, aDst + i * 4096);
      async_ld16(bSrc + (size_t)i * 32 * D_ + kt, bDst + i * 4096);
    }
    __syncthreads();
#pragma unroll
    for (int kk = 0; kk < 64; kk += 32) {
      bf16x8 af[4], bfr[4];
#pragma unroll
      for (int f = 0; f < 4; ++f) {
        af[f]  = *(const bf16x8*)(As + swzg(wm + f * 16 + lrow, kk + lk));
        bfr[f] = *(const bf16x8*)(Bs + swzg(wn + f * 16 + lrow, kk + lk));
      }
#pragma unroll
      for (int fm = 0; fm < 4; ++fm)
#pragma unroll
        for (int fn = 0; fn < 4; ++fn)
          acc[fm][fn] = __builtin_amdgcn_mfma_f32_16x16x32_bf16(
              af[fm], bfr[fn], acc[fm][fn], 0, 0, 0);
    }
    __syncthreads();
  }

#pragma unroll
  for (int fm = 0; fm < 4; ++fm) {
    int rbase = mBase + wm + fm * 16 + (lane >> 4) * 4;
#pragma unroll
    for (int r = 0; r < 4; ++r) {
      int rr = rbase + r;
      float mval = mask[rr];
      int y = target[rr];
      int prev = ((rr & 511) != 0) ? target[rr - 1] : 64;
      int pcv = prev * 65 + y;
      bool idrow = ((rr & 511) != 0);
#pragma unroll
      for (int fn = 0; fn < 4; ++fn) {
        int c = nBase + wn + fn * 16 + lrow;
        float bv = bias[c];
        float e = acc[fm][fn][r] + bv;
        float em = e * mval;
        if (c == pcv) tgtE[rr] = em;  // exact (b,t) target energy
        float fe;
        if (mval != 0.0f) {
          fe = exp2f(em * 1.4426950408889634f);
        } else if (idrow) {
          int ii = c / 65;
          fe = ((c - ii * 65) == ii) ? 1.0f : 0.0f;  // identity transition
        } else {
          fe = 1.0f;  // t==0 masked: exp(0)
        }
        F[(size_t)rr * NP + c] = __float2bfloat16(fe);
      }
    }
  }
}

// ---------------- matrix-chain product kernels ----------------
// MODE 0 (T1): src = F. Block (cx,b): product of 31(30) consecutive F mats.
//   B staged TRANSPOSED into G.  MODE 1 (T2): src = chunkOut, direct copy.
// mfma: C[m][n] = sum_k Als[m][k] * G[n][k]  (G holds B^T)
template <int MODE>
__global__ __launch_bounds__(256, 3) void chain_kernel(
    const __hip_bfloat16* __restrict__ src,
    const int* __restrict__ scIn,
    __hip_bfloat16* __restrict__ outM,
    int* __restrict__ scOut) {
  __shared__ __align__(16) __hip_bfloat16 lds[2 * LMAT2];  // A | G  (48 KiB)
  __shared__ float red[4];
  __hip_bfloat16* Als = lds;
  __hip_bfloat16* Gls = lds + LMAT2;
  ushort* A16 = (ushort*)Als;
  ushort* G16 = (ushort*)Gls;

  int tid = threadIdx.x, wid = tid >> 6, lane = tid & 63;
  int wr = wid >> 1, wc = wid & 1;
  int b = blockIdx.y, cx = blockIdx.x;

  long mat0; int nb, outIdx, Kacc; bool trOut;
  if (MODE == 0) {
    mat0 = (long)b * 512 + (cx == 0 ? 1 : 32 * cx);
    nb = (cx == 0) ? 30 : 31;
    outIdx = b * 16 + cx;
    trOut = (cx & 3) != 0;
    Kacc = 0;
  } else {
    int i0 = b * 16 + 4 * cx;
    mat0 = i0;
    nb = 3;
    outIdx = b * 4 + cx;
    trOut = true;
    Kacc = scIn[i0] + scIn[i0 + 1] + scIn[i0 + 2] + scIn[i0 + 3];
  }

  // zero both buffers (pads must be 0)
  {
    uint4 zz = {0u, 0u, 0u, 0u};
    for (int z = tid; z < 2 * LMAT2 * 2 / 16; z += 256) ((uint4*)lds)[z] = zz;
  }

  // precompute B-staging swizzled LDS offsets (packed lo|hi<<16)
  int nfull = (tid < 64) ? 9 : 8;
  uint bofs[9];
#pragma unroll
  for (int m = 0; m < 9; ++m) {
    uint pk = 0;
    if (m < nfull) {
      int e2 = 2 * (tid + 256 * m);
      int a0 = e2 / 65, b0 = e2 - a0 * 65;
      int a1 = (b0 < 64) ? a0 : a0 + 1, b1 = (b0 < 64) ? b0 + 1 : 0;
      int o0, o1;
      if (MODE == 0) { o0 = swzc(b0, a0); o1 = swzc(b1, a1); }  // transpose
      else           { o0 = swzc(a0, b0); o1 = swzc(a1, b1); }  // copy
      pk = (uint)o0 | ((uint)o1 << 16);
    }
    bofs[m] = pk;
  }
  __syncthreads();  // zero-fill visible

  // A-init: scatter matrix mat0 row-major
  {
    const uint* s32 = (const uint*)(src + (size_t)mat0 * MSTR);
#pragma unroll
    for (int m = 0; m < 9; ++m) {
      if (m < nfull) {
        int e = tid + 256 * m;
        uint v = s32[e];
        int e2 = 2 * e;
        int a0 = e2 / 65, b0 = e2 - a0 * 65;
        int a1 = (b0 < 64) ? a0 : a0 + 1, b1 = (b0 < 64) ? b0 + 1 : 0;
        A16[swzc(a0, b0)] = (ushort)(v & 0xFFFFu);
        A16[swzc(a1, b1)] = (ushort)(v >> 16);
      }
    }
    if (tid == 0) A16[swzc(64, 64)] = ((const ushort*)s32)[4224];
  }

  uint gvA[9], gvB[9];
  ushort tlA = 0, tlB = 0;

  auto issue = [&](uint (&gv)[9], ushort& tl, long mi) {
    const uint* s32 = (const uint*)(src + (size_t)mi * MSTR);
#pragma unroll
    for (int m = 0; m < 9; ++m)
      if (m < nfull) gv[m] = s32[tid + 256 * m];
    if (tid == 0) tl = ((const ushort*)s32)[4224];
  };
  auto stage = [&](const uint (&gv)[9], ushort tl) {
#pragma unroll
    for (int m = 0; m < 9; ++m) {
      if (m < nfull) {
        uint v = gv[m], pk = bofs[m];
        G16[pk & 0xFFFFu] = (ushort)(v & 0xFFFFu);
        G16[pk >> 16] = (ushort)(v >> 16);
      }
    }
    if (tid == 0) G16[swzc(64, 64)] = tl;
  };

  issue(gvA, tlA, mat0 + 1);
  if (nb > 1) issue(gvB, tlB, mat0 + 2);
  stage(gvA, tlA);
  __syncthreads();

  auto stepf = [&](int s, const uint (&gvStage)[9], ushort tlStage,
                   uint (&gvIss)[9], ushort& tlIss) {
    if (s + 2 < nb) issue(gvIss, tlIss, mat0 + 3 + s);  // 2-deep prefetch
    f32x4 acc[3][3];
#pragma unroll
    for (int r = 0; r < 3; ++r)
#pragma unroll
      for (int c = 0; c < 3; ++c) acc[r][c] = (f32x4){0.f, 0.f, 0.f, 0.f};
#pragma unroll
    for (int kk = 0; kk < 96; kk += 32) {
      bf16x8 af[3], bg[3];
      int cb = kk + (lane >> 4) * 8;
#pragma unroll
      for (int r = 0; r < 3; ++r)
        af[r] = *(const bf16x8*)(Als + swzc((3 * wr + r) * 16 + (lane & 15), cb));
#pragma unroll
      for (int c = 0; c < 3; ++c)
        bg[c] = *(const bf16x8*)(Gls + swzc((3 * wc + c) * 16 + (lane & 15), cb));
#pragma unroll
      for (int r = 0; r < 3; ++r)
#pragma unroll
        for (int c = 0; c < 3; ++c)
          acc[r][c] = __builtin_amdgcn_mfma_f32_16x16x32_bf16(af[r], bg[c], acc[r][c], 0, 0, 0);
    }
    // block max -> power-of-2 renorm
    float mx = 0.f;
#pragma unroll
    for (int r = 0; r < 3; ++r)
#pragma unroll
      for (int c = 0; c < 3; ++c)
#pragma unroll
        for (int q = 0; q < 4; ++q) mx = fmaxf(mx, acc[r][c][q]);
#pragma unroll
    for (int o = 32; o; o >>= 1) mx = fmaxf(mx, __shfl_xor(mx, o));
    if (lane == 0) red[wid] = mx;
    __syncthreads();  // B1: red visible; all MFMA reads of Als & Gls done
    mx = fmaxf(fmaxf(red[0], red[1]), fmaxf(red[2], red[3]));
    int k; frexpf(mx, &k);
    Kacc += k;
    float sc = ldexpf(1.0f, -k);
    bool last = (s == nb - 1);
#pragma unroll
    for (int r = 0; r < 3; ++r) {
      int R0 = (3 * wr + r) * 16 + (lane >> 4) * 4;
#pragma unroll
      for (int c = 0; c < 3; ++c) {
        int C0 = (3 * wc + c) * 16 + (lane & 15);
#pragma unroll
        for (int q = 0; q < 4; ++q) {
          __hip_bfloat16 h = __float2bfloat16(acc[r][c][q] * sc);
          if (!last) {
            Als[swzc(R0 + q, C0)] = h;
          } else if (R0 + q < K_ && C0 < K_) {
            size_t oo = (size_t)outIdx * MSTR +
                        (trOut ? (C0 * 65 + R0 + q) : ((R0 + q) * 65 + C0));
            outM[oo] = h;
          }
        }
      }
    }
    if (s + 1 < nb) stage(gvStage, tlStage);
    __syncthreads();  // B2: Als writeback + new G visible
  };

  for (int s = 0; s < nb; s += 2) {
    stepf(s, gvB, tlB, gvA, tlA);
    if (s + 1 < nb) stepf(s + 1, gvA, tlA, gvB, tlB);
  }
  if (tid == 0) scOut[outIdx] = Kacc;
}

// ---------------- final: p0 through 4 matrices, logsumexp, -tgt ----------------
__global__ __launch_bounds__(256) void final_kernel(
    const __hip_bfloat16* __restrict__ F, const __hip_bfloat16* __restrict__ levA,
    const int* __restrict__ sc2, const float* __restrict__ tgtE,
    float* __restrict__ out) {
  __shared__ float v[2][80];
  __shared__ float rs[8];
  int b = blockIdx.x, tid = threadIdx.x;
  if (tid < K_)
    v[0][tid] = __bfloat162float(F[(size_t)b * 512 * NP + 64 * 65 + tid]);
  __syncthreads();
  int cur = 0;
  for (int m = 0; m < 4; ++m) {
    const __hip_bfloat16* T = levA + (size_t)(b * 4 + m) * MSTR;  // transposed [j][i]
    if (tid < K_) {
      float s = 0.f;
      for (int i = 0; i < K_; ++i)
        s += v[cur][i] * __bfloat162float(T[tid * 65 + i]);
      v[1 - cur][tid] = s;
    }
    cur ^= 1;
    __syncthreads();
  }
  float tv = tgtE[b * 512 + tid] + tgtE[b * 512 + 256 + tid];
#pragma unroll
  for (int o = 32; o; o >>= 1) tv += __shfl_xor(tv, o);
  if ((tid & 63) == 0) rs[4 + (tid >> 6)] = tv;
  if (tid < 64) {
    float zz = v[cur][tid] + ((tid == 0) ? v[cur][64] : 0.f);
#pragma unroll
    for (int o = 32; o; o >>= 1) zz += __shfl_xor(zz, o);
    if (tid == 0) rs[0] = zz;
  }
  __syncthreads();
  if (tid == 0) {
    float tg = rs[4] + rs[5] + rs[6] + rs[7];
    int S = sc2[4 * b] + sc2[4 * b + 1] + sc2[4 * b + 2] + sc2[4 * b + 3];
    out[b] = logf(rs[0]) + 0.6931471805599453f * (float)S - tg;
  }
}

// ---------------- launch ----------------
extern "C" void kernel_launch(void* const* d_in, const int* in_sizes, int n_in,
                              void* d_out, int out_size, void* d_ws, size_t ws_size,
                              hipStream_t stream) {
  const float* x      = (const float*)d_in[0];
  const float* Ws     = (const float*)d_in[1];
  const float* bs     = (const float*)d_in[2];
  const float* Wt     = (const float*)d_in[3];
  const float* bt     = (const float*)d_in[4];
  const int*   target = (const int*)d_in[5];
  const float* mask   = (const float*)d_in[6];
  float* out = (float*)d_out;

  char* ws = (char*)d_ws;
  __hip_bfloat16* xbf  = (__hip_bfloat16*)(ws);               // 8,388,608 B (dead after GEMM)
  __hip_bfloat16* wbf  = (__hip_bfloat16*)(ws + 8388608);     // 2,228,224 B (dead after GEMM)
  float*          bias = (float*)(ws + 10616832);             // 17,408 B
  __hip_bfloat16* F    = (__hip_bfloat16*)(ws + 10634240);    // 142,606,336 B
  float*          tgtE = (float*)(ws + 153240576);            // 65,536 B
  // region reuse (after GEMM no longer needs xbf/wbf):
  __hip_bfloat16* chunkOut = (__hip_bfloat16*)(ws);           // 512*8704 = 4,456,448 B
  __hip_bfloat16* levA     = (__hip_bfloat16*)(ws + 8388608); // 128*8704 = 1,114,112 B
  int*            sc1      = (int*)(ws + 9502720);            // 2,048 B
  int*            sc2      = (int*)(ws + 9504768);            // 512 B

  hipLaunchKernelGGL(pack_w_kernel, dim3(NP), dim3(256), 0, stream,
                     Ws, Wt, bs, bt, wbf, bias);
  hipLaunchKernelGGL(pack_x_kernel, dim3(M_ * D_ / 4 / 256), dim3(256), 0, stream,
                     x, xbf);
  hipLaunchKernelGGL(gemm_exp_kernel, dim3(M_ / 128, NP / 128), dim3(256), 0, stream,
                     xbf, wbf, bias, mask, target, F, tgtE);
  hipLaunchKernelGGL((chain_kernel<0>), dim3(16, 32), dim3(256), 0, stream,
                     F, (const int*)nullptr, chunkOut, sc1);
  hipLaunchKernelGGL((chain_kernel<1>), dim3(4, 32), dim3(256), 0, stream,
                     chunkOut, sc1, levA, sc2);
  hipLaunchKernelGGL(final_kernel, dim3(B_), dim3(256), 0, stream,
                     F, levA, sc2, tgtE, out);
}